// Round 1
// baseline (8268.436 us; speedup 1.0000x reference)
//
#include <hip/hip_runtime.h>

typedef unsigned short u16;
typedef unsigned int u32;
typedef __attribute__((ext_vector_type(8))) short bf16x8;
typedef __attribute__((ext_vector_type(4))) float f32x4;
typedef const __attribute__((address_space(1))) void* gas1_t;
typedef __attribute__((address_space(3))) void* las3_t;

// Problem dims
#define T_LEN 512
#define B_SZ  64
#define D_SZ  1024
#define H_SZ  1024
#define N4    4096     // 4*H (stacked gates i,f,o,c~)
#define TB    32768    // T*B

// workspace layout (bytes), all 256-aligned
#define OFF_WX    0UL          // 8 MiB  bf16 Wx  [4096][1024]
#define OFF_WH    8388608UL    // 8 MiB  bf16 Wh  [4096][1024]
#define OFF_BIAS  16777216UL   // 16 KiB f32 bias[4096] = bx+bh
#define OFF_HBUF  16793600UL   // 256 KiB bf16 hbuf[2][64][1024]
#define OFF_FLAGS 17055744UL   // 1 KiB  u32 flags[256] (grid barrier)
#define OFF_XBF   17056768UL   // 64 MiB bf16 x [32768][1024]
#define OFF_XPROJ 84165632UL   // 256 MiB bf16 xproj [32768][4096]

__device__ __forceinline__ u16 f2bf(float f) {
  u32 u = __builtin_bit_cast(u32, f);
  u += 0x7FFFu + ((u >> 16) & 1u);   // RNE
  return (u16)(u >> 16);
}
__device__ __forceinline__ float bf2f(u16 h) {
  u32 u = ((u32)h) << 16;
  return __builtin_bit_cast(float, u);
}

// ---------- phase 0: conversions ----------
__global__ __launch_bounds__(256) void cvt_f32_bf16(const float* __restrict__ in,
                                                    u16* __restrict__ out, int n) {
  int i = (blockIdx.x * 256 + threadIdx.x) * 4;
  if (i >= n) return;
  float4 v = *(const float4*)(in + i);
  ushort4 o;
  o.x = f2bf(v.x); o.y = f2bf(v.y); o.z = f2bf(v.z); o.w = f2bf(v.w);
  *(ushort4*)(out + i) = o;
}

__global__ __launch_bounds__(256) void bias_add(const float* __restrict__ a,
                                                const float* __restrict__ b,
                                                float* __restrict__ o) {
  int i = blockIdx.x * 256 + threadIdx.x;  // 4096 total
  o[i] = a[i] + b[i];
}

// ---------- phase 1: xproj = x @ Wx^T (bf16 MFMA, 128x128 tile, BK=64) ----------
// A [32768][1024] bf16 row-major; Bw [4096][1024] bf16 row-major (B^T form); C [32768][4096] bf16
__global__ __launch_bounds__(256) void gemm_xproj(const u16* __restrict__ A,
                                                  const u16* __restrict__ Bw,
                                                  u16* __restrict__ C) {
  __shared__ __align__(16) u16 As[128 * 64];
  __shared__ __align__(16) u16 Bs[128 * 64];
  int wg = blockIdx.x;
  // XCD-aware bijective swizzle: 8192 % 8 == 0
  int swz = (wg & 7) * 1024 + (wg >> 3);
  int mb = swz >> 5;   // 0..255
  int nb = swz & 31;   // 0..31
  int tid = threadIdx.x;
  int lane = tid & 63;
  int w = tid >> 6;
  int wm = w >> 1, wn = w & 1;

  int srow = lane >> 3;          // 0..7 row within 8-row chunk
  int scol = (lane & 7) * 8;     // k-elem offset, 16B per lane
  const u16* Abase = A + (size_t)(mb * 128) * 1024;
  const u16* Bbase = Bw + (size_t)(nb * 128) * 1024;

  f32x4 acc[4][4];
#pragma unroll
  for (int i = 0; i < 4; ++i)
#pragma unroll
    for (int j = 0; j < 4; ++j) acc[i][j] = f32x4{0.f, 0.f, 0.f, 0.f};

  for (int k0 = 0; k0 < 1024; k0 += 64) {
#pragma unroll
    for (int r = 0; r < 4; ++r) {
      int chunk = w * 4 + r;           // 0..15, wave-uniform
      int row = chunk * 8 + srow;      // 0..127
      __builtin_amdgcn_global_load_lds((gas1_t)(const void*)(Abase + (size_t)row * 1024 + k0 + scol),
                                       (las3_t)(void*)(&As[chunk * 512]), 16, 0, 0);
      __builtin_amdgcn_global_load_lds((gas1_t)(const void*)(Bbase + (size_t)row * 1024 + k0 + scol),
                                       (las3_t)(void*)(&Bs[chunk * 512]), 16, 0, 0);
    }
    __syncthreads();
#pragma unroll
    for (int kk = 0; kk < 64; kk += 32) {
      bf16x8 af[4], bfr[4];
#pragma unroll
      for (int mt = 0; mt < 4; ++mt)
        af[mt] = *(const bf16x8*)&As[(wm * 64 + mt * 16 + (lane & 15)) * 64 + kk + ((lane >> 4) << 3)];
#pragma unroll
      for (int nt = 0; nt < 4; ++nt)
        bfr[nt] = *(const bf16x8*)&Bs[(wn * 64 + nt * 16 + (lane & 15)) * 64 + kk + ((lane >> 4) << 3)];
#pragma unroll
      for (int mt = 0; mt < 4; ++mt)
#pragma unroll
        for (int nt = 0; nt < 4; ++nt)
          acc[mt][nt] = __builtin_amdgcn_mfma_f32_16x16x32_bf16(af[mt], bfr[nt], acc[mt][nt], 0, 0, 0);
    }
    __syncthreads();
  }
  int crowbase = mb * 128 + wm * 64;
  int ccolbase = nb * 128 + wn * 64;
#pragma unroll
  for (int mt = 0; mt < 4; ++mt)
#pragma unroll
    for (int nt = 0; nt < 4; ++nt) {
      int col = ccolbase + nt * 16 + (lane & 15);
#pragma unroll
      for (int r = 0; r < 4; ++r) {
        int row = crowbase + mt * 16 + ((lane >> 4) << 2) + r;
        C[(size_t)row * 4096 + col] = f2bf(acc[mt][nt][r]);
      }
    }
}

// ---------- phase 2: persistent sequential LSTM ----------
// 256 WGs: wg = bh*128 + hs. WG owns batch-half bh (32 rows) x 8 h-cols (hs*8..+8) -> 32 gate-cols.
// Wh fragments live in registers for all 512 steps. K split across 4 waves (256 each),
// partial sums reduced via LDS. h double-buffered in global (bf16) + flag-array grid barrier.
__global__ __launch_bounds__(256, 2) void lstm_seq(const u16* __restrict__ xproj,
                                                   const u16* __restrict__ Whb,
                                                   const float* __restrict__ bias,
                                                   u16* __restrict__ hbuf,
                                                   u32* __restrict__ flags,
                                                   float* __restrict__ out) {
  __shared__ float pacc[16 * 256];  // [frag 0..15][16x16 f32]
  int wg = blockIdx.x;
  int bh = wg >> 7;       // batch half
  int hs = wg & 127;      // h-col slice
  int tid = threadIdx.x;
  int lane = tid & 63;
  int w = tid >> 6;       // wave -> K-slice
  int kw = w << 8;        // k base (256 per wave)

  // preload Wh fragments: wf[nt][ks], nt: gate-col tile (16 cols), ks: k-step of 32
  bf16x8 wf[2][8];
#pragma unroll
  for (int nt = 0; nt < 2; ++nt) {
    int c = nt * 16 + (lane & 15);                      // 0..31 col in slice
    int wrow = ((c >> 3) << 10) + (hs << 3) + (c & 7);  // gate*1024 + hs*8 + jj
#pragma unroll
    for (int ks = 0; ks < 8; ++ks)
      wf[nt][ks] = *(const bf16x8*)&Whb[(size_t)wrow * 1024 + kw + ks * 32 + ((lane >> 4) << 3)];
  }

  int b = tid >> 3;                  // 0..31 batch row within half
  int jj = tid & 7;                  // h-col within slice
  int hrow = (bh << 5) + b;          // 0..63
  int hcol = (hs << 3) + jj;         // 0..1023
  float bs0 = bias[hcol], bs1 = bias[1024 + hcol], bs2 = bias[2048 + hcol], bs3 = bias[3072 + hcol];
  float c_state = 0.f;
  int am_row0 = (bh << 5) + (lane & 15);
  int am_row1 = am_row0 + 16;
  int mI = b >> 4, r16 = b & 15;

  for (int t = 0; t < T_LEN; ++t) {
    const u16* hcur = hbuf + (size_t)(t & 1) * 65536;
    // prefetch xproj early (independent of h)
    const u16* xp = xproj + ((size_t)(t * 64 + hrow)) * 4096;
    u16 xp0 = xp[hcol], xp1 = xp[1024 + hcol], xp2 = xp[2048 + hcol], xp3 = xp[3072 + hcol];

    f32x4 acc00 = f32x4{0.f,0.f,0.f,0.f}, acc01 = acc00, acc10 = acc00, acc11 = acc00;
#pragma unroll
    for (int ks = 0; ks < 8; ++ks) {
      bf16x8 a0 = *(const bf16x8*)&hcur[(size_t)am_row0 * 1024 + kw + ks * 32 + ((lane >> 4) << 3)];
      bf16x8 a1 = *(const bf16x8*)&hcur[(size_t)am_row1 * 1024 + kw + ks * 32 + ((lane >> 4) << 3)];
      acc00 = __builtin_amdgcn_mfma_f32_16x16x32_bf16(a0, wf[0][ks], acc00, 0, 0, 0);
      acc01 = __builtin_amdgcn_mfma_f32_16x16x32_bf16(a0, wf[1][ks], acc01, 0, 0, 0);
      acc10 = __builtin_amdgcn_mfma_f32_16x16x32_bf16(a1, wf[0][ks], acc10, 0, 0, 0);
      acc11 = __builtin_amdgcn_mfma_f32_16x16x32_bf16(a1, wf[1][ks], acc11, 0, 0, 0);
    }
    // write per-wave partials: frag id = w*4 + m*2 + nt, layout [row16][col16]
    {
      int rbase = ((lane >> 4) << 2);
      int cidx = lane & 15;
#pragma unroll
      for (int r = 0; r < 4; ++r) {
        pacc[((w * 4 + 0) << 8) + ((rbase + r) << 4) + cidx] = acc00[r];
        pacc[((w * 4 + 1) << 8) + ((rbase + r) << 4) + cidx] = acc01[r];
        pacc[((w * 4 + 2) << 8) + ((rbase + r) << 4) + cidx] = acc10[r];
        pacc[((w * 4 + 3) << 8) + ((rbase + r) << 4) + cidx] = acc11[r];
      }
    }
    __syncthreads();
    // per-thread gather: reduce 4 wave-partials for each of 4 gates
    float g[4];
#pragma unroll
    for (int gate = 0; gate < 4; ++gate) {
      int cc = gate * 8 + jj;
      int nt = cc >> 4, c16 = cc & 15;
      float s = 0.f;
#pragma unroll
      for (int w2 = 0; w2 < 4; ++w2)
        s += pacc[((w2 * 4 + mI * 2 + nt) << 8) + (r16 << 4) + c16];
      g[gate] = s;
    }
    float gi = g[0] + bf2f(xp0) + bs0;
    float gf = g[1] + bf2f(xp1) + bs1;
    float go = g[2] + bf2f(xp2) + bs2;
    float gc = g[3] + bf2f(xp3) + bs3;
    float iv = 1.f / (1.f + __expf(-gi));
    float fv = 1.f / (1.f + __expf(-gf));
    float ov = 1.f / (1.f + __expf(-go));
    float cv = tanhf(gc);
    c_state = 1.f / (1.f + __expf(-(fv * c_state + iv * cv)));  // nonstandard, per reference
    float hn = tanhf(c_state) * ov;
    hbuf[(size_t)((t & 1) ^ 1) * 65536 + (size_t)hrow * 1024 + hcol] = f2bf(hn);

    if (t == T_LEN - 1) {
      out[(size_t)hrow * 1024 + hcol] = hn;
    } else {
      // grid barrier: own-flag release store, poll all 256 flags, acquire fence
      __syncthreads();
      if (tid < 64) {
        if (tid == 0)
          __hip_atomic_store(&flags[wg], (u32)(t + 1), __ATOMIC_RELEASE, __HIP_MEMORY_SCOPE_AGENT);
        u32 tgt = (u32)(t + 1);
        int i0 = tid * 4;
        for (;;) {
          u32 f0 = __hip_atomic_load(&flags[i0 + 0], __ATOMIC_RELAXED, __HIP_MEMORY_SCOPE_AGENT);
          u32 f1 = __hip_atomic_load(&flags[i0 + 1], __ATOMIC_RELAXED, __HIP_MEMORY_SCOPE_AGENT);
          u32 f2 = __hip_atomic_load(&flags[i0 + 2], __ATOMIC_RELAXED, __HIP_MEMORY_SCOPE_AGENT);
          u32 f3 = __hip_atomic_load(&flags[i0 + 3], __ATOMIC_RELAXED, __HIP_MEMORY_SCOPE_AGENT);
          if (__all((f0 >= tgt) && (f1 >= tgt) && (f2 >= tgt) && (f3 >= tgt))) break;
        }
        __builtin_amdgcn_fence(__ATOMIC_ACQUIRE, "agent");  // invalidate L1 + XCD L2
      }
      __syncthreads();
    }
  }
}

extern "C" void kernel_launch(void* const* d_in, const int* in_sizes, int n_in,
                              void* d_out, int out_size, void* d_ws, size_t ws_size,
                              hipStream_t stream) {
  const float* x  = (const float*)d_in[0];   // [512][64][1024]
  const float* Wx = (const float*)d_in[1];   // [4][1024][1024]
  const float* bx = (const float*)d_in[2];   // [4][1024]
  const float* Wh = (const float*)d_in[3];   // [4][1024][1024]
  const float* bh = (const float*)d_in[4];   // [4][1024]
  float* out = (float*)d_out;                // [64][1024]
  char* ws = (char*)d_ws;

  u16* wx_bf  = (u16*)(ws + OFF_WX);
  u16* wh_bf  = (u16*)(ws + OFF_WH);
  float* bias = (float*)(ws + OFF_BIAS);
  u16* hbuf   = (u16*)(ws + OFF_HBUF);
  u32* flags  = (u32*)(ws + OFF_FLAGS);
  u16* x_bf   = (u16*)(ws + OFF_XBF);
  u16* xproj  = (u16*)(ws + OFF_XPROJ);

  // zero hbuf[0..1] + flags (contiguous 263168 bytes)
  hipMemsetAsync(ws + OFF_HBUF, 0, 263168, stream);

  cvt_f32_bf16<<<4096, 256, 0, stream>>>(Wx, wx_bf, 4194304);
  cvt_f32_bf16<<<4096, 256, 0, stream>>>(Wh, wh_bf, 4194304);
  bias_add<<<16, 256, 0, stream>>>(bx, bh, bias);
  cvt_f32_bf16<<<32768, 256, 0, stream>>>(x, x_bf, 33554432);
  gemm_xproj<<<8192, 256, 0, stream>>>(x_bf, wx_bf, xproj);
  lstm_seq<<<256, 256, 0, stream>>>(xproj, wh_bf, bias, hbuf, flags, out);
}

// Round 2
// 4554.412 us; speedup vs baseline: 1.8155x; 1.8155x over previous
//
#include <hip/hip_runtime.h>

typedef unsigned short u16;
typedef unsigned int u32;
typedef __attribute__((ext_vector_type(8))) short bf16x8;
typedef __attribute__((ext_vector_type(4))) float f32x4;
typedef __attribute__((ext_vector_type(4))) u32 u32x4;
typedef const __attribute__((address_space(1))) void* gas1_t;
typedef __attribute__((address_space(3))) void* las3_t;

// Problem dims
#define T_LEN 512
#define B_SZ  64
#define D_SZ  1024
#define H_SZ  1024

// workspace layout (bytes), all 256-aligned
#define OFF_WX    0UL          // 8 MiB  bf16 Wx  [4096][1024]
#define OFF_WH    8388608UL    // 8 MiB  bf16 Wh  [4096][1024]
#define OFF_BIAS  16777216UL   // 16 KiB f32 bias[4096] = bx+bh
#define OFF_HBUF  16793600UL   // 256 KiB bf16 hbuf[2][64][1024]
#define OFF_FLAGS 17055744UL   // 1 KiB  u32 flags[256] (grid barrier)
#define OFF_XBF   17056768UL   // 64 MiB bf16 x [32768][1024]
#define OFF_XPROJ 84165632UL   // 256 MiB bf16 xproj [32768][4096]

__device__ __forceinline__ u16 f2bf(float f) {
  u32 u = __builtin_bit_cast(u32, f);
  u += 0x7FFFu + ((u >> 16) & 1u);   // RNE
  return (u16)(u >> 16);
}
__device__ __forceinline__ float bf2f(u16 h) {
  u32 u = ((u32)h) << 16;
  return __builtin_bit_cast(float, u);
}

// ---------- phase 0: conversions ----------
__global__ __launch_bounds__(256) void cvt_f32_bf16(const float* __restrict__ in,
                                                    u16* __restrict__ out, int n) {
  int i = (blockIdx.x * 256 + threadIdx.x) * 4;
  if (i >= n) return;
  float4 v = *(const float4*)(in + i);
  ushort4 o;
  o.x = f2bf(v.x); o.y = f2bf(v.y); o.z = f2bf(v.z); o.w = f2bf(v.w);
  *(ushort4*)(out + i) = o;
}

__global__ __launch_bounds__(256) void bias_add(const float* __restrict__ a,
                                                const float* __restrict__ b,
                                                float* __restrict__ o) {
  int i = blockIdx.x * 256 + threadIdx.x;  // 4096 total
  o[i] = a[i] + b[i];
}

// ---------- phase 1: xproj = x @ Wx^T (bf16 MFMA, 128x128 tile, BK=64) ----------
__global__ __launch_bounds__(256) void gemm_xproj(const u16* __restrict__ A,
                                                  const u16* __restrict__ Bw,
                                                  u16* __restrict__ C) {
  __shared__ __align__(16) u16 As[128 * 64];
  __shared__ __align__(16) u16 Bs[128 * 64];
  int wg = blockIdx.x;
  int swz = (wg & 7) * 1024 + (wg >> 3);  // XCD-aware bijective (8192 % 8 == 0)
  int mb = swz >> 5;
  int nb = swz & 31;
  int tid = threadIdx.x;
  int lane = tid & 63;
  int w = tid >> 6;
  int wm = w >> 1, wn = w & 1;

  int srow = lane >> 3;
  int scol = (lane & 7) * 8;
  const u16* Abase = A + (size_t)(mb * 128) * 1024;
  const u16* Bbase = Bw + (size_t)(nb * 128) * 1024;

  f32x4 acc[4][4];
#pragma unroll
  for (int i = 0; i < 4; ++i)
#pragma unroll
    for (int j = 0; j < 4; ++j) acc[i][j] = f32x4{0.f, 0.f, 0.f, 0.f};

  for (int k0 = 0; k0 < 1024; k0 += 64) {
#pragma unroll
    for (int r = 0; r < 4; ++r) {
      int chunk = w * 4 + r;
      int row = chunk * 8 + srow;
      __builtin_amdgcn_global_load_lds((gas1_t)(const void*)(Abase + (size_t)row * 1024 + k0 + scol),
                                       (las3_t)(void*)(&As[chunk * 512]), 16, 0, 0);
      __builtin_amdgcn_global_load_lds((gas1_t)(const void*)(Bbase + (size_t)row * 1024 + k0 + scol),
                                       (las3_t)(void*)(&Bs[chunk * 512]), 16, 0, 0);
    }
    __syncthreads();
#pragma unroll
    for (int kk = 0; kk < 64; kk += 32) {
      bf16x8 af[4], bfr[4];
#pragma unroll
      for (int mt = 0; mt < 4; ++mt)
        af[mt] = *(const bf16x8*)&As[(wm * 64 + mt * 16 + (lane & 15)) * 64 + kk + ((lane >> 4) << 3)];
#pragma unroll
      for (int nt = 0; nt < 4; ++nt)
        bfr[nt] = *(const bf16x8*)&Bs[(wn * 64 + nt * 16 + (lane & 15)) * 64 + kk + ((lane >> 4) << 3)];
#pragma unroll
      for (int mt = 0; mt < 4; ++mt)
#pragma unroll
        for (int nt = 0; nt < 4; ++nt)
          acc[mt][nt] = __builtin_amdgcn_mfma_f32_16x16x32_bf16(af[mt], bfr[nt], acc[mt][nt], 0, 0, 0);
    }
    __syncthreads();
  }
  int crowbase = mb * 128 + wm * 64;
  int ccolbase = nb * 128 + wn * 64;
#pragma unroll
  for (int mt = 0; mt < 4; ++mt)
#pragma unroll
    for (int nt = 0; nt < 4; ++nt) {
      int col = ccolbase + nt * 16 + (lane & 15);
#pragma unroll
      for (int r = 0; r < 4; ++r) {
        int row = crowbase + mt * 16 + ((lane >> 4) << 2) + r;
        C[(size_t)row * 4096 + col] = f2bf(acc[mt][nt][r]);
      }
    }
}

// ---------- phase 2: persistent sequential LSTM ----------
// Cross-XCD coherence WITHOUT L2 wbl2/inv fences: every cross-step access uses
// sc0 sc1 (bypass L1 + per-XCD L2; coherence point = die-level LLC). Ordering
// via s_waitcnt vmcnt(0) only. h double-buffered; flag t+1 set only after
// step-t reads complete, so buffer reuse at t+1 cannot race.
__global__ __launch_bounds__(256, 2) void lstm_seq(const u16* __restrict__ xproj,
                                                   const u16* __restrict__ Whb,
                                                   const float* __restrict__ bias,
                                                   u16* __restrict__ hbuf,
                                                   u32* __restrict__ flags,
                                                   float* __restrict__ out) {
  __shared__ float pacc[16 * 256];  // [frag 0..15][16x16 f32]
  int wg = blockIdx.x;
  int bh = wg >> 7;       // batch half
  int hs = wg & 127;      // h-col slice (8 cols)
  int tid = threadIdx.x;
  int lane = tid & 63;
  int w = tid >> 6;       // wave -> K-slice
  int kw = w << 8;        // k base (256 per wave)
  int hi8 = (lane >> 4) << 3;

  // preload Wh fragments (resident in registers for all 512 steps)
  bf16x8 wf[2][8];
#pragma unroll
  for (int nt = 0; nt < 2; ++nt) {
    int c = nt * 16 + (lane & 15);
    int wrow = ((c >> 3) << 10) + (hs << 3) + (c & 7);  // gate*1024 + hs*8 + jj
#pragma unroll
    for (int ks = 0; ks < 8; ++ks)
      wf[nt][ks] = *(const bf16x8*)&Whb[(size_t)wrow * 1024 + kw + ks * 32 + hi8];
  }

  int b = tid >> 3;                  // 0..31 batch row within half
  int jj = tid & 7;                  // h-col within slice
  int hrow = (bh << 5) + b;
  int hcol = (hs << 3) + jj;
  float bs0 = bias[hcol], bs1 = bias[1024 + hcol], bs2 = bias[2048 + hcol], bs3 = bias[3072 + hcol];
  float c_state = 0.f;
  int am_row0 = (bh << 5) + (lane & 15);
  int am_row1 = am_row0 + 16;
  int mI = b >> 4, r16 = b & 15;

  for (int t = 0; t < T_LEN; ++t) {
    const u16* hcur = hbuf + (size_t)(t & 1) * 65536;
    // xproj prefetch (normal cached loads; read-only data)
    const u16* xp = xproj + ((size_t)(t * 64 + hrow)) * 4096;
    u16 xp0 = xp[hcol], xp1 = xp[1024 + hcol], xp2 = xp[2048 + hcol], xp3 = xp[3072 + hcol];

    // --- coherent h load: 16x dwordx4 + waitcnt in ONE asm (outputs valid on exit) ---
    const u16* p0 = hcur + (size_t)am_row0 * 1024 + kw + hi8;
    const u16* p1 = hcur + (size_t)am_row1 * 1024 + kw + hi8;
    u32x4 r0, r1, r2, r3, r4, r5, r6, r7, r8, r9, r10, r11, r12, r13, r14, r15;
    asm volatile(
        "global_load_dwordx4 %0, %16, off sc0 sc1\n\t"
        "global_load_dwordx4 %1, %16, off offset:64 sc0 sc1\n\t"
        "global_load_dwordx4 %2, %16, off offset:128 sc0 sc1\n\t"
        "global_load_dwordx4 %3, %16, off offset:192 sc0 sc1\n\t"
        "global_load_dwordx4 %4, %16, off offset:256 sc0 sc1\n\t"
        "global_load_dwordx4 %5, %16, off offset:320 sc0 sc1\n\t"
        "global_load_dwordx4 %6, %16, off offset:384 sc0 sc1\n\t"
        "global_load_dwordx4 %7, %16, off offset:448 sc0 sc1\n\t"
        "global_load_dwordx4 %8, %17, off sc0 sc1\n\t"
        "global_load_dwordx4 %9, %17, off offset:64 sc0 sc1\n\t"
        "global_load_dwordx4 %10, %17, off offset:128 sc0 sc1\n\t"
        "global_load_dwordx4 %11, %17, off offset:192 sc0 sc1\n\t"
        "global_load_dwordx4 %12, %17, off offset:256 sc0 sc1\n\t"
        "global_load_dwordx4 %13, %17, off offset:320 sc0 sc1\n\t"
        "global_load_dwordx4 %14, %17, off offset:384 sc0 sc1\n\t"
        "global_load_dwordx4 %15, %17, off offset:448 sc0 sc1\n\t"
        "s_waitcnt vmcnt(0)"
        : "=&v"(r0), "=&v"(r1), "=&v"(r2), "=&v"(r3),
          "=&v"(r4), "=&v"(r5), "=&v"(r6), "=&v"(r7),
          "=&v"(r8), "=&v"(r9), "=&v"(r10), "=&v"(r11),
          "=&v"(r12), "=&v"(r13), "=&v"(r14), "=&v"(r15)
        : "v"(p0), "v"(p1)
        : "memory");
    bf16x8 a0s[8] = {__builtin_bit_cast(bf16x8, r0),  __builtin_bit_cast(bf16x8, r1),
                     __builtin_bit_cast(bf16x8, r2),  __builtin_bit_cast(bf16x8, r3),
                     __builtin_bit_cast(bf16x8, r4),  __builtin_bit_cast(bf16x8, r5),
                     __builtin_bit_cast(bf16x8, r6),  __builtin_bit_cast(bf16x8, r7)};
    bf16x8 a1s[8] = {__builtin_bit_cast(bf16x8, r8),  __builtin_bit_cast(bf16x8, r9),
                     __builtin_bit_cast(bf16x8, r10), __builtin_bit_cast(bf16x8, r11),
                     __builtin_bit_cast(bf16x8, r12), __builtin_bit_cast(bf16x8, r13),
                     __builtin_bit_cast(bf16x8, r14), __builtin_bit_cast(bf16x8, r15)};

    f32x4 acc00 = f32x4{0.f, 0.f, 0.f, 0.f}, acc01 = acc00, acc10 = acc00, acc11 = acc00;
#pragma unroll
    for (int ks = 0; ks < 8; ++ks) {
      acc00 = __builtin_amdgcn_mfma_f32_16x16x32_bf16(a0s[ks], wf[0][ks], acc00, 0, 0, 0);
      acc01 = __builtin_amdgcn_mfma_f32_16x16x32_bf16(a0s[ks], wf[1][ks], acc01, 0, 0, 0);
      acc10 = __builtin_amdgcn_mfma_f32_16x16x32_bf16(a1s[ks], wf[0][ks], acc10, 0, 0, 0);
      acc11 = __builtin_amdgcn_mfma_f32_16x16x32_bf16(a1s[ks], wf[1][ks], acc11, 0, 0, 0);
    }
    // per-wave partials -> LDS
    {
      int rbase = ((lane >> 4) << 2);
      int cidx = lane & 15;
#pragma unroll
      for (int r = 0; r < 4; ++r) {
        pacc[((w * 4 + 0) << 8) + ((rbase + r) << 4) + cidx] = acc00[r];
        pacc[((w * 4 + 1) << 8) + ((rbase + r) << 4) + cidx] = acc01[r];
        pacc[((w * 4 + 2) << 8) + ((rbase + r) << 4) + cidx] = acc10[r];
        pacc[((w * 4 + 3) << 8) + ((rbase + r) << 4) + cidx] = acc11[r];
      }
    }
    __syncthreads();
    float g[4];
#pragma unroll
    for (int gate = 0; gate < 4; ++gate) {
      int cc = gate * 8 + jj;
      int nt = cc >> 4, c16 = cc & 15;
      float s = 0.f;
#pragma unroll
      for (int w2 = 0; w2 < 4; ++w2)
        s += pacc[((w2 * 4 + mI * 2 + nt) << 8) + (r16 << 4) + c16];
      g[gate] = s;
    }
    float gi = g[0] + bf2f(xp0) + bs0;
    float gf = g[1] + bf2f(xp1) + bs1;
    float go = g[2] + bf2f(xp2) + bs2;
    float gc = g[3] + bf2f(xp3) + bs3;
    float iv = 1.f / (1.f + __expf(-gi));
    float fv = 1.f / (1.f + __expf(-gf));
    float ov = 1.f / (1.f + __expf(-go));
    float cv = tanhf(gc);
    c_state = 1.f / (1.f + __expf(-(fv * c_state + iv * cv)));  // nonstandard, per reference
    float hn = tanhf(c_state) * ov;

    if (t == T_LEN - 1) {
      out[(size_t)hrow * 1024 + hcol] = hn;
    } else {
      // coherent h store (write-through to LLC)
      u16* hdst = hbuf + (size_t)((t & 1) ^ 1) * 65536 + (size_t)hrow * 1024 + hcol;
      u32 hb = (u32)f2bf(hn);
      asm volatile("global_store_short %0, %1, off sc0 sc1" :: "v"(hdst), "v"(hb) : "memory");
      // drain own stores to coherence point, then workgroup-sync
      asm volatile("s_waitcnt vmcnt(0)" ::: "memory");
      __syncthreads();  // need pacc reads done anyway before next iter overwrite
      u32 tgt = (u32)(t + 1);
      if (tid == 0) {
        u32* fp = flags + wg;
        asm volatile("global_store_dword %0, %1, off sc0 sc1" :: "v"(fp), "v"(tgt) : "memory");
      }
      if (tid < 64) {
        const u32* fp = flags + (tid << 2);
        for (;;) {
          u32x4 f;
          asm volatile("global_load_dwordx4 %0, %1, off sc0 sc1\n\ts_waitcnt vmcnt(0)"
                       : "=v"(f) : "v"(fp) : "memory");
          if (__all((f.x >= tgt) && (f.y >= tgt) && (f.z >= tgt) && (f.w >= tgt))) break;
        }
      }
      __syncthreads();
    }
  }
}

extern "C" void kernel_launch(void* const* d_in, const int* in_sizes, int n_in,
                              void* d_out, int out_size, void* d_ws, size_t ws_size,
                              hipStream_t stream) {
  const float* x  = (const float*)d_in[0];   // [512][64][1024]
  const float* Wx = (const float*)d_in[1];   // [4][1024][1024]
  const float* bx = (const float*)d_in[2];   // [4][1024]
  const float* Wh = (const float*)d_in[3];   // [4][1024][1024]
  const float* bh = (const float*)d_in[4];   // [4][1024]
  float* out = (float*)d_out;                // [64][1024]
  char* ws = (char*)d_ws;

  u16* wx_bf  = (u16*)(ws + OFF_WX);
  u16* wh_bf  = (u16*)(ws + OFF_WH);
  float* bias = (float*)(ws + OFF_BIAS);
  u16* hbuf   = (u16*)(ws + OFF_HBUF);
  u32* flags  = (u32*)(ws + OFF_FLAGS);
  u16* x_bf   = (u16*)(ws + OFF_XBF);
  u16* xproj  = (u16*)(ws + OFF_XPROJ);

  // zero hbuf[0..1] + flags (contiguous 263168 bytes)
  hipMemsetAsync(ws + OFF_HBUF, 0, 263168, stream);

  cvt_f32_bf16<<<4096, 256, 0, stream>>>(Wx, wx_bf, 4194304);
  cvt_f32_bf16<<<4096, 256, 0, stream>>>(Wh, wh_bf, 4194304);
  bias_add<<<16, 256, 0, stream>>>(bx, bh, bias);
  cvt_f32_bf16<<<32768, 256, 0, stream>>>(x, x_bf, 33554432);
  gemm_xproj<<<8192, 256, 0, stream>>>(x_bf, wx_bf, xproj);
  lstm_seq<<<256, 256, 0, stream>>>(xproj, wh_bf, bias, hbuf, flags, out);
}